// Round 8
// baseline (240.468 us; speedup 1.0000x reference)
//
#include <hip/hip_runtime.h>
#include <hip/hip_bf16.h>

typedef __attribute__((ext_vector_type(8))) short short8;
typedef __attribute__((ext_vector_type(4))) float f32x4;

static constexpr int B_ = 64;
static constexpr int N_ = 4096;
static constexpr int V_ = 21;
static constexpr int S_ = 50;
static constexpr int E_ = 64;
static constexpr int H_ = 128;
static constexpr int NPAIR = V_ * V_;   // 441
static constexpr int NTAB = NPAIR * S_; // 22050

__device__ __forceinline__ float rcp_(float x) { return __builtin_amdgcn_rcpf(x); }
__device__ __forceinline__ float sigm(float x) { return rcp_(1.0f + __expf(-x)); }
__device__ __forceinline__ float tanh_(float x) {
  float a = fabsf(x);
  float e = __expf(-2.0f * a);
  float t = (1.0f - e) * rcp_(1.0f + e);
  return x < 0.0f ? -t : t;
}
__device__ __forceinline__ unsigned short f2bf(float f) {
  __hip_bfloat16 b = __float2bfloat16(f);
  return *reinterpret_cast<unsigned short*>(&b);
}
__device__ __forceinline__ float bf2f(unsigned short u) {
  return __uint_as_float(((unsigned int)u) << 16);
}

struct Gates { float cv, hv; };
// sx: gate-interleaved symx entry for this (s, cc): {i, o, u, f}
__device__ __forceinline__ Gates gate_combine(float4 sx,
    float i_p, float o_p, float u_p, float fl_p, float fr_p, float cl, float cr) {
  float gi = sigm(sx.x + i_p);
  float go = sigm(sx.y + o_p);
  float gu = tanh_(sx.z + u_p);
  float fl = sigm(sx.w + fl_p);
  float fr = sigm(sx.w + fr_p);
  float cv = fmaf(gi, gu, fmaf(fl, cl, fr * cr));
  Gates g; g.cv = cv; g.hv = go * tanh_(cv);
  return g;
}

// ---- pre0: weight transposes ----
// 0..31: Wfrag (bf16 MFMA B-frags of U); 32..63: Wt = U k-major [128][512];
// 64..95: Wxt = Wx k-major; 96: Wpt = Wp.T; 97: Woutt = Wout.T.
__global__ void k_pre0(const float* __restrict__ Ui, const float* __restrict__ Uo,
                       const float* __restrict__ Uu, const float* __restrict__ Uf,
                       const float* __restrict__ Wi, const float* __restrict__ Wo,
                       const float* __restrict__ Wu, const float* __restrict__ Wf,
                       const float* __restrict__ Wp, const float* __restrict__ Wout,
                       unsigned short* __restrict__ Wfrag, float* __restrict__ Wt,
                       float* __restrict__ Wxt, float* __restrict__ Wpt,
                       float* __restrict__ Woutt) {
  int blk = blockIdx.x, t = threadIdx.x;
  if (blk < 32) {
    int idx = blk * 256 + t;
    int L = idx & 63;
    int K = (idx >> 6) & 3;
    int T = idx >> 8;
    int n = 16 * T + (L & 15);
    int k0 = 32 * K + ((L >> 4) << 3);
    int g = n >> 7, o = n & 127;
    const float* U = (g == 0) ? Ui : (g == 1) ? Uo : (g == 2) ? Uu : Uf;
    unsigned short out[8];
    #pragma unroll
    for (int j = 0; j < 8; ++j) out[j] = f2bf(U[o * 128 + k0 + j]);
    *(int4*)(Wfrag + (size_t)idx * 8) = *(int4*)out;
  } else if (blk < 96) {
    bool isU = blk < 64;
    int base = (((blk & 31)) * 256 + t) * 8;
    int k = base >> 9;
    int col = base & 511;
    int gg = col >> 7, o0 = col & 127;
    const float* M;
    if (isU) M = (gg == 0) ? Ui : (gg == 1) ? Uo : (gg == 2) ? Uu : Uf;
    else     M = (gg == 0) ? Wi : (gg == 1) ? Wo : (gg == 2) ? Wu : Wf;
    float* D = isU ? Wt : Wxt;
    float v[8];
    #pragma unroll
    for (int j = 0; j < 8; ++j) v[j] = M[(o0 + j) * 128 + k];
    *(float4*)(D + base) = *(float4*)v;
    *(float4*)(D + base + 4) = *(float4*)(v + 4);
  } else if (blk == 96) {
    for (int i = t; i < E_ * H_; i += 256) {
      int e = i >> 7, o = i & 127;
      Wpt[i] = Wp[o * E_ + e];
    }
  } else {
    for (int i = t; i < H_ * H_; i += 256) {
      int k = i >> 7, o = i & 127;
      Woutt[i] = Wout[o * H_ + k];
    }
  }
}

// ---- pre1: leaf (blocks 0..20) + symx gate-interleaved (21..70) ----
__global__ void k_pre1(const float* __restrict__ emb, const float* __restrict__ sym_emb,
                       const float* __restrict__ Wpt, const float* __restrict__ Wxt,
                       const float* __restrict__ bp, const float* __restrict__ bi,
                       const float* __restrict__ bo, const float* __restrict__ bu,
                       const float* __restrict__ bfv,
                       unsigned short* __restrict__ leaf_h8, float* __restrict__ leaf_c,
                       float* __restrict__ symx) {
  int blk = blockIdx.x, t = threadIdx.x;
  __shared__ float x[128];
  if (blk < V_) {
    int v = blk;
    float acc = bp[t];
    if (v != 0) {  // reference zeroes emb row 0
      for (int e = 0; e < E_; ++e) acc = fmaf(emb[v * E_ + e], Wpt[e * 128 + t], acc);
    }
    x[t] = acc;
    __syncthreads();
    float zi = bi[t], zo = bo[t], zu = bu[t];
    for (int k = 0; k < H_; ++k) {
      float xv = x[k];
      const float* wr = Wxt + k * 512;
      zi = fmaf(xv, wr[t], zi);
      zo = fmaf(xv, wr[128 + t], zo);
      zu = fmaf(xv, wr[256 + t], zu);
    }
    float gi = sigm(zi), go = sigm(zo), gu = tanh_(zu);
    float c = gi * gu;
    leaf_c[v * H_ + t] = c;
    leaf_h8[v * H_ + t] = f2bf(go * tanh_(c));
  } else {
    int s = blk - V_;
    float acc = bp[t];
    for (int e = 0; e < E_; ++e) acc = fmaf(sym_emb[s * E_ + e], Wpt[e * 128 + t], acc);
    x[t] = acc;
    __syncthreads();
    float zi = bi[t], zo = bo[t], zu = bu[t], zf = bfv[t];
    for (int k = 0; k < H_; ++k) {
      float xv = x[k];
      const float* wr = Wxt + k * 512;
      zi = fmaf(xv, wr[t], zi);
      zo = fmaf(xv, wr[128 + t], zo);
      zu = fmaf(xv, wr[256 + t], zu);
      zf = fmaf(xv, wr[384 + t], zf);
    }
    // gate-interleaved: symx[s*512 + cc*4 + {i,o,u,f}]
    float4 v4 = make_float4(zi, zo, zu, zf);
    *(float4*)(symx + (size_t)s * 512 + t * 4) = v4;
  }
}

// ---- table phase A: per-pair matvec pre-activations (coalesced via Wt) ----
__global__ void k_tabA(const unsigned short* __restrict__ leaf_h8, const float* __restrict__ Wt,
                       float* __restrict__ za) {
  int p = blockIdx.x, t = threadIdx.x;  // 441 x 128
  int tl = p / V_, tr = p % V_;
  __shared__ float hl[128], hr[128];
  hl[t] = bf2f(leaf_h8[tl * H_ + t]);
  hr[t] = bf2f(leaf_h8[tr * H_ + t]);
  __syncthreads();
  float zi = 0.f, zo = 0.f, zu = 0.f, pfl = 0.f, pfr = 0.f;
  for (int k = 0; k < H_; ++k) {
    float l = hl[k], r = hr[k], ht = l + r;
    const float* wr = Wt + k * 512;
    zi = fmaf(ht, wr[t], zi);
    zo = fmaf(ht, wr[128 + t], zo);
    zu = fmaf(ht, wr[256 + t], zu);
    float wf = wr[384 + t];
    pfl = fmaf(l, wf, pfl);
    pfr = fmaf(r, wf, pfr);
  }
  float* z = za + (size_t)p * 640;
  z[t] = zi; z[128 + t] = zo; z[256 + t] = zu; z[384 + t] = pfl; z[512 + t] = pfr;
}

// ---- table phase B: gate epilogue over 22050 rows + idx1 build ----
__global__ void k_tabB(const float* __restrict__ za, const float* __restrict__ symx,
                       const float* __restrict__ leaf_c,
                       const int* __restrict__ tokens, const int* __restrict__ symbols,
                       unsigned short* __restrict__ tab_h8, float* __restrict__ tab_c,
                       int* __restrict__ idx1) {
  int blk = blockIdx.x, t = threadIdx.x;
  if (blk < NTAB / 2) {
    int row = blk * 2 + (t >> 7);
    int u = t & 127;
    int p = row / S_, s = row - p * S_;
    int tl = p / V_, tr = p - tl * V_;
    const float* z = za + (size_t)p * 640;
    float4 sx = *(const float4*)(symx + (size_t)s * 512 + u * 4);
    Gates gt = gate_combine(sx, z[u], z[128 + u], z[256 + u], z[384 + u], z[512 + u],
                            leaf_c[tl * H_ + u], leaf_c[tr * H_ + u]);
    tab_c[(size_t)row * H_ + u] = gt.cv;
    tab_h8[(size_t)row * H_ + u] = f2bf(gt.hv);
  } else {
    int g = (blk - NTAB / 2) * 256 + t;
    int b = g >> 11, j = g & 2047;
    idx1[g] = (tokens[b * N_ + 2 * j] * V_ + tokens[b * N_ + 2 * j + 1]) * S_ + symbols[b * (N_ - 1) + j];
  }
}

// ---- fused levels 2+3 with register prefetch of gathers ----
__global__ void __launch_bounds__(512, 6) k_lvl23(
    const unsigned short* __restrict__ Wfrag, const float* __restrict__ symx,
    const int* __restrict__ symbols, const int* __restrict__ idx1,
    const unsigned short* __restrict__ gh8, const float* __restrict__ gc,
    unsigned short* __restrict__ h_out8, float* __restrict__ c_out) {
  __shared__ __align__(16) unsigned short Ag[64][136];
  __shared__ __align__(16) unsigned short Bh[32][136];
  __shared__ float Bc[32][132];
  int t = threadIdx.x;
  int w = t >> 6, L = t & 63, q = L >> 4, cL = L & 15;
  int cc = 16 * w + cL;
  int g0 = blockIdx.x * 32;
  int b = g0 >> 10;
  int j2 = g0 & 1023;
  const int* sym_b = symbols + (size_t)b * (N_ - 1);
  const int* gix = idx1 + 2 * g0;

  #pragma unroll
  for (int i = 0; i < 2; ++i) {
    int fid = t + 512 * i;
    int row = fid >> 4, co = (fid & 15) * 8;
    *(int4*)&Ag[row][co] = *(const int4*)(gh8 + (size_t)gix[row] * H_ + co);
  }
  __syncthreads();

  const short8* wf = (const short8*)Wfrag;
  // level 2: 2 chunks of 16 nodes; outputs -> LDS
  #pragma unroll
  for (int c = 0; c < 2; ++c) {
    // prefetch this chunk's c-gathers + symbol indices (consumed in epilogue)
    float clp[4], crp[4];
    int spre[4];
    #pragma unroll
    for (int it = 0; it < 4; ++it) {
      int n = 16 * c + 8 * (it >> 1) + 2 * q + (it & 1);
      clp[it] = gc[(size_t)gix[2 * n] * H_ + cc];
      crp[it] = gc[(size_t)gix[2 * n + 1] * H_ + cc];
      spre[it] = sym_b[2048 + j2 + n];
    }
    f32x4 acc[2][4];
    #pragma unroll
    for (int r = 0; r < 2; ++r)
      #pragma unroll
      for (int g = 0; g < 4; ++g) acc[r][g] = (f32x4){0.f, 0.f, 0.f, 0.f};
    #pragma unroll
    for (int K = 0; K < 4; ++K) {
      short8 bfr[4];
      #pragma unroll
      for (int g = 0; g < 4; ++g) bfr[g] = wf[(size_t)((w + 8 * g) * 4 + K) * 64 + L];
      short8 a0 = *(const short8*)&Ag[32 * c + cL][K * 32 + q * 8];
      short8 a1 = *(const short8*)&Ag[32 * c + 16 + cL][K * 32 + q * 8];
      #pragma unroll
      for (int g = 0; g < 4; ++g) {
        acc[0][g] = __builtin_amdgcn_mfma_f32_16x16x32_bf16(a0, bfr[g], acc[0][g], 0, 0, 0);
        acc[1][g] = __builtin_amdgcn_mfma_f32_16x16x32_bf16(a1, bfr[g], acc[1][g], 0, 0, 0);
      }
    }
    #pragma unroll
    for (int r = 0; r < 2; ++r) {
      #pragma unroll
      for (int nd = 0; nd < 2; ++nd) {
        int it = r * 2 + nd;
        int n = 16 * c + 8 * r + 2 * q + nd;
        float4 sx = *(const float4*)(symx + (size_t)spre[it] * 512 + cc * 4);
        Gates gt = gate_combine(sx,
            acc[r][0][2 * nd] + acc[r][0][2 * nd + 1],
            acc[r][1][2 * nd] + acc[r][1][2 * nd + 1],
            acc[r][2][2 * nd] + acc[r][2][2 * nd + 1],
            acc[r][3][2 * nd], acc[r][3][2 * nd + 1], clp[it], crp[it]);
        Bc[n][cc] = gt.cv;
        Bh[n][cc] = f2bf(gt.hv);
      }
    }
  }
  __syncthreads();
  // level 3
  {
    int spre[4];
    #pragma unroll
    for (int it = 0; it < 4; ++it) {
      int n = 8 * (it >> 1) + 2 * q + (it & 1);
      spre[it] = sym_b[3072 + (j2 >> 1) + n];
    }
    f32x4 acc[2][4];
    #pragma unroll
    for (int r = 0; r < 2; ++r)
      #pragma unroll
      for (int g = 0; g < 4; ++g) acc[r][g] = (f32x4){0.f, 0.f, 0.f, 0.f};
    #pragma unroll
    for (int K = 0; K < 4; ++K) {
      short8 bfr[4];
      #pragma unroll
      for (int g = 0; g < 4; ++g) bfr[g] = wf[(size_t)((w + 8 * g) * 4 + K) * 64 + L];
      short8 a0 = *(const short8*)&Bh[cL][K * 32 + q * 8];
      short8 a1 = *(const short8*)&Bh[16 + cL][K * 32 + q * 8];
      #pragma unroll
      for (int g = 0; g < 4; ++g) {
        acc[0][g] = __builtin_amdgcn_mfma_f32_16x16x32_bf16(a0, bfr[g], acc[0][g], 0, 0, 0);
        acc[1][g] = __builtin_amdgcn_mfma_f32_16x16x32_bf16(a1, bfr[g], acc[1][g], 0, 0, 0);
      }
    }
    #pragma unroll
    for (int r = 0; r < 2; ++r) {
      #pragma unroll
      for (int nd = 0; nd < 2; ++nd) {
        int it = r * 2 + nd;
        int n = 8 * r + 2 * q + nd;
        int G3 = (g0 >> 1) + n;
        float4 sx = *(const float4*)(symx + (size_t)spre[it] * 512 + cc * 4);
        Gates gt = gate_combine(sx,
            acc[r][0][2 * nd] + acc[r][0][2 * nd + 1],
            acc[r][1][2 * nd] + acc[r][1][2 * nd + 1],
            acc[r][2][2 * nd] + acc[r][2][2 * nd + 1],
            acc[r][3][2 * nd], acc[r][3][2 * nd + 1],
            Bc[2 * n][cc], Bc[2 * n + 1][cc]);
        c_out[(size_t)G3 * H_ + cc] = gt.cv;
        h_out8[(size_t)G3 * H_ + cc] = f2bf(gt.hv);
      }
    }
  }
}

// ---- fused levels 4+5 (dense input) with prefetch ----
__global__ void __launch_bounds__(512, 6) k_lvl45(
    const unsigned short* __restrict__ Wfrag, const float* __restrict__ symx,
    const int* __restrict__ symbols,
    const unsigned short* __restrict__ in_h8, const float* __restrict__ in_c,
    unsigned short* __restrict__ h_out8, float* __restrict__ c_out) {
  __shared__ __align__(16) unsigned short Ag[64][136];
  __shared__ __align__(16) unsigned short Bh[32][136];
  __shared__ float Bc[32][132];
  int t = threadIdx.x;
  int w = t >> 6, L = t & 63, q = L >> 4, cL = L & 15;
  int cc = 16 * w + cL;
  int g0 = blockIdx.x * 32;
  int b = g0 >> 8;
  int j4 = g0 & 255;
  const int* sym_b = symbols + (size_t)b * (N_ - 1);

  #pragma unroll
  for (int i = 0; i < 2; ++i) {
    int fid = t + 512 * i;
    int row = fid >> 4, co = (fid & 15) * 8;
    *(int4*)&Ag[row][co] = *(const int4*)(in_h8 + (size_t)(2 * g0 + row) * H_ + co);
  }
  __syncthreads();

  const short8* wf = (const short8*)Wfrag;
  #pragma unroll
  for (int c = 0; c < 2; ++c) {
    float clp[4], crp[4];
    int spre[4];
    #pragma unroll
    for (int it = 0; it < 4; ++it) {
      int n = 16 * c + 8 * (it >> 1) + 2 * q + (it & 1);
      int g = g0 + n;
      clp[it] = in_c[(size_t)(2 * g) * H_ + cc];
      crp[it] = in_c[(size_t)(2 * g + 1) * H_ + cc];
      spre[it] = sym_b[3584 + j4 + n];
    }
    f32x4 acc[2][4];
    #pragma unroll
    for (int r = 0; r < 2; ++r)
      #pragma unroll
      for (int g = 0; g < 4; ++g) acc[r][g] = (f32x4){0.f, 0.f, 0.f, 0.f};
    #pragma unroll
    for (int K = 0; K < 4; ++K) {
      short8 bfr[4];
      #pragma unroll
      for (int g = 0; g < 4; ++g) bfr[g] = wf[(size_t)((w + 8 * g) * 4 + K) * 64 + L];
      short8 a0 = *(const short8*)&Ag[32 * c + cL][K * 32 + q * 8];
      short8 a1 = *(const short8*)&Ag[32 * c + 16 + cL][K * 32 + q * 8];
      #pragma unroll
      for (int g = 0; g < 4; ++g) {
        acc[0][g] = __builtin_amdgcn_mfma_f32_16x16x32_bf16(a0, bfr[g], acc[0][g], 0, 0, 0);
        acc[1][g] = __builtin_amdgcn_mfma_f32_16x16x32_bf16(a1, bfr[g], acc[1][g], 0, 0, 0);
      }
    }
    #pragma unroll
    for (int r = 0; r < 2; ++r) {
      #pragma unroll
      for (int nd = 0; nd < 2; ++nd) {
        int it = r * 2 + nd;
        int n = 16 * c + 8 * r + 2 * q + nd;
        float4 sx = *(const float4*)(symx + (size_t)spre[it] * 512 + cc * 4);
        Gates gt = gate_combine(sx,
            acc[r][0][2 * nd] + acc[r][0][2 * nd + 1],
            acc[r][1][2 * nd] + acc[r][1][2 * nd + 1],
            acc[r][2][2 * nd] + acc[r][2][2 * nd + 1],
            acc[r][3][2 * nd], acc[r][3][2 * nd + 1], clp[it], crp[it]);
        Bc[n][cc] = gt.cv;
        Bh[n][cc] = f2bf(gt.hv);
      }
    }
  }
  __syncthreads();
  {
    int spre[4];
    #pragma unroll
    for (int it = 0; it < 4; ++it) {
      int n = 8 * (it >> 1) + 2 * q + (it & 1);
      spre[it] = sym_b[3840 + (j4 >> 1) + n];
    }
    f32x4 acc[2][4];
    #pragma unroll
    for (int r = 0; r < 2; ++r)
      #pragma unroll
      for (int g = 0; g < 4; ++g) acc[r][g] = (f32x4){0.f, 0.f, 0.f, 0.f};
    #pragma unroll
    for (int K = 0; K < 4; ++K) {
      short8 bfr[4];
      #pragma unroll
      for (int g = 0; g < 4; ++g) bfr[g] = wf[(size_t)((w + 8 * g) * 4 + K) * 64 + L];
      short8 a0 = *(const short8*)&Bh[cL][K * 32 + q * 8];
      short8 a1 = *(const short8*)&Bh[16 + cL][K * 32 + q * 8];
      #pragma unroll
      for (int g = 0; g < 4; ++g) {
        acc[0][g] = __builtin_amdgcn_mfma_f32_16x16x32_bf16(a0, bfr[g], acc[0][g], 0, 0, 0);
        acc[1][g] = __builtin_amdgcn_mfma_f32_16x16x32_bf16(a1, bfr[g], acc[1][g], 0, 0, 0);
      }
    }
    #pragma unroll
    for (int r = 0; r < 2; ++r) {
      #pragma unroll
      for (int nd = 0; nd < 2; ++nd) {
        int it = r * 2 + nd;
        int n = 8 * r + 2 * q + nd;
        int G5 = (g0 >> 1) + n;
        float4 sx = *(const float4*)(symx + (size_t)spre[it] * 512 + cc * 4);
        Gates gt = gate_combine(sx,
            acc[r][0][2 * nd] + acc[r][0][2 * nd + 1],
            acc[r][1][2 * nd] + acc[r][1][2 * nd + 1],
            acc[r][2][2 * nd] + acc[r][2][2 * nd + 1],
            acc[r][3][2 * nd], acc[r][3][2 * nd + 1],
            Bc[2 * n][cc], Bc[2 * n + 1][cc]);
        c_out[(size_t)G5 * H_ + cc] = gt.cv;
        h_out8[(size_t)G5 * H_ + cc] = f2bf(gt.hv);
      }
    }
  }
}

// ---- dense level 6 with prefetch ----
__global__ void __launch_bounds__(512, 2) k_lvl6(
    const unsigned short* __restrict__ Wfrag, const float* __restrict__ symx,
    const int* __restrict__ symbols,
    const unsigned short* __restrict__ h_prev8, const float* __restrict__ c_prev,
    unsigned short* __restrict__ h_out8, float* __restrict__ c_out) {
  __shared__ __align__(16) unsigned short Asm[32][136];
  int t = threadIdx.x;
  int w = t >> 6, L = t & 63, q = L >> 4, cL = L & 15;
  int cc = 16 * w + cL;
  int g0 = blockIdx.x * 16;

  float clp[4], crp[4];
  int spre[4];
  #pragma unroll
  for (int it = 0; it < 4; ++it) {
    int n = 8 * (it >> 1) + 2 * q + (it & 1);
    int g = g0 + n;
    clp[it] = c_prev[(size_t)(2 * g) * H_ + cc];
    crp[it] = c_prev[(size_t)(2 * g + 1) * H_ + cc];
    int bb = g >> 6, jj = g & 63;
    spre[it] = symbols[bb * (N_ - 1) + 3968 + jj];
  }
  {
    int row = t >> 4, co = (t & 15) * 8;
    *(int4*)&Asm[row][co] = *(const int4*)(h_prev8 + (size_t)(2 * g0 + row) * H_ + co);
  }
  __syncthreads();

  f32x4 acc[2][4];
  #pragma unroll
  for (int r = 0; r < 2; ++r)
    #pragma unroll
    for (int g = 0; g < 4; ++g) acc[r][g] = (f32x4){0.f, 0.f, 0.f, 0.f};

  const short8* wf = (const short8*)Wfrag;
  #pragma unroll
  for (int K = 0; K < 4; ++K) {
    short8 bfr[4];
    #pragma unroll
    for (int g = 0; g < 4; ++g) bfr[g] = wf[(size_t)((w + 8 * g) * 4 + K) * 64 + L];
    short8 a0 = *(const short8*)&Asm[cL][K * 32 + q * 8];
    short8 a1 = *(const short8*)&Asm[16 + cL][K * 32 + q * 8];
    #pragma unroll
    for (int g = 0; g < 4; ++g) {
      acc[0][g] = __builtin_amdgcn_mfma_f32_16x16x32_bf16(a0, bfr[g], acc[0][g], 0, 0, 0);
      acc[1][g] = __builtin_amdgcn_mfma_f32_16x16x32_bf16(a1, bfr[g], acc[1][g], 0, 0, 0);
    }
  }

  #pragma unroll
  for (int r = 0; r < 2; ++r) {
    #pragma unroll
    for (int nd = 0; nd < 2; ++nd) {
      int it = r * 2 + nd;
      int n = 8 * r + 2 * q + nd;
      int g = g0 + n;
      float4 sx = *(const float4*)(symx + (size_t)spre[it] * 512 + cc * 4);
      Gates gt = gate_combine(sx,
          acc[r][0][2 * nd] + acc[r][0][2 * nd + 1],
          acc[r][1][2 * nd] + acc[r][1][2 * nd + 1],
          acc[r][2][2 * nd] + acc[r][2][2 * nd + 1],
          acc[r][3][2 * nd], acc[r][3][2 * nd + 1], clp[it], crp[it]);
      c_out[(size_t)g * H_ + cc] = gt.cv;
      h_out8[(size_t)g * H_ + cc] = f2bf(gt.hv);
    }
  }
}

// ---- deep: levels 7-12 + fused output projection; ping-pong LDS, 1 barrier/level ----
__global__ void __launch_bounds__(512, 1) k_deep(
    const unsigned short* __restrict__ Wfrag, const float* __restrict__ symx,
    const int* __restrict__ symbols,
    const unsigned short* __restrict__ in_h8, const float* __restrict__ in_c,
    const float* __restrict__ Woutt, const float* __restrict__ bout,
    float* __restrict__ out) {
  __shared__ __align__(16) unsigned short Ah0[64][136];
  __shared__ __align__(16) unsigned short Ah1[32][136];
  __shared__ float Cs0[64][128];
  __shared__ float Cs1[32][128];
  __shared__ float rootv[128];
  int t = threadIdx.x;
  int w = t >> 6, L = t & 63, q = L >> 4, cL = L & 15;
  int cc = 16 * w + cL;
  int b = blockIdx.x;

  #pragma unroll
  for (int i = 0; i < 2; ++i) {
    int fid = t + 512 * i;
    int row = fid >> 4, co = (fid & 15) * 8;
    *(int4*)&Ah0[row][co] = *(const int4*)(in_h8 + (size_t)(b * 64 + row) * H_ + co);
  }
  #pragma unroll
  for (int i = 0; i < 4; ++i) {
    int fid = t + 512 * i;
    int row = fid >> 5, c4 = (fid & 31) << 2;
    *(float4*)&Cs0[row][c4] = *(const float4*)(in_c + (size_t)(b * 64 + row) * H_ + c4);
  }
  __syncthreads();

  const short8* wf = (const short8*)Wfrag;
  int R = 64;
  #pragma unroll
  for (int lev = 0; lev < 6; ++lev) {
    const int l = 7 + lev;
    const int nodes = R >> 1;
    const int jb = b * (N_ - 1) + (N_ - (N_ >> (l - 1)));
    const int nchunk = (R + 31) >> 5;
    unsigned short (*Ard)[136] = (lev & 1) ? Ah1 : Ah0;
    unsigned short (*Awr)[136] = (lev & 1) ? Ah0 : Ah1;
    const float* crd = (lev & 1) ? &Cs1[0][0] : &Cs0[0][0];
    float* cwr = (lev & 1) ? &Cs0[0][0] : &Cs1[0][0];
    // prefetch this level's symbol indices
    int spre[8];
    for (int it = 0; it < 4 * nchunk; ++it) {
      int n = 16 * (it >> 2) + 8 * ((it >> 1) & 1) + 2 * q + (it & 1);
      spre[it] = (n < nodes) ? symbols[jb + n] : 0;
    }
    for (int c = 0; c < nchunk; ++c) {
      f32x4 acc[2][4];
      #pragma unroll
      for (int r = 0; r < 2; ++r)
        #pragma unroll
        for (int g = 0; g < 4; ++g) acc[r][g] = (f32x4){0.f, 0.f, 0.f, 0.f};
      #pragma unroll
      for (int K = 0; K < 4; ++K) {
        short8 bfr[4];
        #pragma unroll
        for (int g = 0; g < 4; ++g) bfr[g] = wf[(size_t)((w + 8 * g) * 4 + K) * 64 + L];
        short8 a0 = *(const short8*)&Ard[32 * c + cL][K * 32 + q * 8];
        short8 a1 = *(const short8*)&Ard[32 * c + 16 + cL][K * 32 + q * 8];
        #pragma unroll
        for (int g = 0; g < 4; ++g) {
          acc[0][g] = __builtin_amdgcn_mfma_f32_16x16x32_bf16(a0, bfr[g], acc[0][g], 0, 0, 0);
          acc[1][g] = __builtin_amdgcn_mfma_f32_16x16x32_bf16(a1, bfr[g], acc[1][g], 0, 0, 0);
        }
      }
      #pragma unroll
      for (int r = 0; r < 2; ++r) {
        #pragma unroll
        for (int nd = 0; nd < 2; ++nd) {
          int it = c * 4 + r * 2 + nd;
          int n = 16 * c + 8 * r + 2 * q + nd;
          if (n < nodes) {
            float4 sx = *(const float4*)(symx + (size_t)spre[it] * 512 + cc * 4);
            Gates gt = gate_combine(sx,
                acc[r][0][2 * nd] + acc[r][0][2 * nd + 1],
                acc[r][1][2 * nd] + acc[r][1][2 * nd + 1],
                acc[r][2][2 * nd] + acc[r][2][2 * nd + 1],
                acc[r][3][2 * nd], acc[r][3][2 * nd + 1],
                crd[(size_t)(2 * n) * 128 + cc], crd[(size_t)(2 * n + 1) * 128 + cc]);
            if (lev == 5) {
              rootv[cc] = gt.hv;
            } else {
              cwr[(size_t)n * 128 + cc] = gt.cv;
              Awr[n][cc] = f2bf(gt.hv);
            }
          }
        }
      }
    }
    __syncthreads();
    R >>= 1;
  }
  // fused projection: out[b] = rootv @ Woutt + bout
  if (t < 128) {
    float acc = bout[t];
    for (int k = 0; k < H_; ++k) acc = fmaf(rootv[k], Woutt[k * 128 + t], acc);
    out[(size_t)b * H_ + t] = acc;
  }
}

extern "C" void kernel_launch(void* const* d_in, const int* in_sizes, int n_in,
                              void* d_out, int out_size, void* d_ws, size_t ws_size,
                              hipStream_t stream) {
  const int* tokens    = (const int*)d_in[0];
  const int* symbols   = (const int*)d_in[1];
  const float* emb     = (const float*)d_in[2];
  const float* sym_emb = (const float*)d_in[3];
  const float* Wp  = (const float*)d_in[4];
  const float* bp  = (const float*)d_in[5];
  const float* Wi  = (const float*)d_in[6];
  const float* bi  = (const float*)d_in[7];
  const float* Ui  = (const float*)d_in[8];
  const float* Wf  = (const float*)d_in[9];
  const float* bf  = (const float*)d_in[10];
  const float* Uf  = (const float*)d_in[11];
  const float* Wo  = (const float*)d_in[12];
  const float* bo  = (const float*)d_in[13];
  const float* Uo  = (const float*)d_in[14];
  const float* Wu  = (const float*)d_in[15];
  const float* bu  = (const float*)d_in[16];
  const float* Uu  = (const float*)d_in[17];
  const float* Wout= (const float*)d_in[18];
  const float* bout= (const float*)d_in[19];

  // Workspace layout (~54 MB)
  char* ws = (char*)d_ws;
  unsigned short* Wfrag   = (unsigned short*)(ws);                  // 131072
  float*          Wt      = (float*)(ws + 131072);                  // 262144
  float*          Wxt     = (float*)(ws + 393216);                  // 262144
  float*          Wpt     = (float*)(ws + 655360);                  // 32768
  float*          Woutt   = (float*)(ws + 688128);                  // 65536
  unsigned short* leaf_h8 = (unsigned short*)(ws + 753664);         // 5376
  float*          leaf_c  = (float*)(ws + 759040);                  // 10752
  float*          symx    = (float*)(ws + 769792);                  // 102400
  float*          za      = (float*)(ws + 872192);                  // 1128960
  unsigned short* tab_h8  = (unsigned short*)(ws + 2001152UL);      // 5644800
  float*          tab_c   = (float*)(ws + 7645952UL);               // 11289600
  int*            idx1    = (int*)(ws + 18935552UL);                // 524288
  unsigned short* L3h8    = (unsigned short*)(ws + 19459840UL);     // 8388608
  float*          L3c     = (float*)(ws + 27848448UL);              // 16777216
  unsigned short* L5h8    = (unsigned short*)(ws + 44625664UL);     // 2097152
  float*          L5c     = (float*)(ws + 46722816UL);              // 4194304
  unsigned short* L6h8    = (unsigned short*)(ws + 50917120UL);     // 1048576
  float*          L6c     = (float*)(ws + 51965696UL);              // 2097152

  k_pre0<<<98, 256, 0, stream>>>(Ui, Uo, Uu, Uf, Wi, Wo, Wu, Wf, Wp, Wout,
                                 Wfrag, Wt, Wxt, Wpt, Woutt);
  k_pre1<<<V_ + S_, 128, 0, stream>>>(emb, sym_emb, Wpt, Wxt,
                                      bp, bi, bo, bu, bf, leaf_h8, leaf_c, symx);
  k_tabA<<<NPAIR, 128, 0, stream>>>(leaf_h8, Wt, za);
  k_tabB<<<NTAB / 2 + 512, 256, 0, stream>>>(za, symx, leaf_c, tokens, symbols,
                                             tab_h8, tab_c, idx1);
  k_lvl23<<<2048, 512, 0, stream>>>(Wfrag, symx, symbols, idx1, tab_h8, tab_c, L3h8, L3c);
  k_lvl45<<<512, 512, 0, stream>>>(Wfrag, symx, symbols, L3h8, L3c, L5h8, L5c);
  k_lvl6<<<256, 512, 0, stream>>>(Wfrag, symx, symbols, L5h8, L5c, L6h8, L6c);
  k_deep<<<B_, 512, 0, stream>>>(Wfrag, symx, symbols, L6h8, L6c, Woutt, bout,
                                 (float*)d_out);
}

// Round 9
// 221.667 us; speedup vs baseline: 1.0848x; 1.0848x over previous
//
#include <hip/hip_runtime.h>
#include <hip/hip_bf16.h>

typedef __attribute__((ext_vector_type(8))) short short8;
typedef __attribute__((ext_vector_type(4))) float f32x4;

static constexpr int B_ = 64;
static constexpr int N_ = 4096;
static constexpr int V_ = 21;
static constexpr int S_ = 50;
static constexpr int E_ = 64;
static constexpr int H_ = 128;
static constexpr int NPAIR = V_ * V_;   // 441
static constexpr int NTAB = NPAIR * S_; // 22050

__device__ __forceinline__ float rcp_(float x) { return __builtin_amdgcn_rcpf(x); }
__device__ __forceinline__ float sigm(float x) { return rcp_(1.0f + __expf(-x)); }
__device__ __forceinline__ float tanh_(float x) {
  float a = fabsf(x);
  float e = __expf(-2.0f * a);
  float t = (1.0f - e) * rcp_(1.0f + e);
  return x < 0.0f ? -t : t;
}
__device__ __forceinline__ unsigned short f2bf(float f) {
  __hip_bfloat16 b = __float2bfloat16(f);
  return *reinterpret_cast<unsigned short*>(&b);
}
__device__ __forceinline__ float bf2f(unsigned short u) {
  return __uint_as_float(((unsigned int)u) << 16);
}

struct Gates { float cv, hv; };
// sx: gate-interleaved symx entry for this (s, cc): {i, o, u, f}
__device__ __forceinline__ Gates gate_combine(float4 sx,
    float i_p, float o_p, float u_p, float fl_p, float fr_p, float cl, float cr) {
  float gi = sigm(sx.x + i_p);
  float go = sigm(sx.y + o_p);
  float gu = tanh_(sx.z + u_p);
  float fl = sigm(sx.w + fl_p);
  float fr = sigm(sx.w + fr_p);
  float cv = fmaf(gi, gu, fmaf(fl, cl, fr * cr));
  Gates g; g.cv = cv; g.hv = go * tanh_(cv);
  return g;
}

// ---- pre0: weight transposes ----
__global__ void k_pre0(const float* __restrict__ Ui, const float* __restrict__ Uo,
                       const float* __restrict__ Uu, const float* __restrict__ Uf,
                       const float* __restrict__ Wi, const float* __restrict__ Wo,
                       const float* __restrict__ Wu, const float* __restrict__ Wf,
                       const float* __restrict__ Wp, const float* __restrict__ Wout,
                       unsigned short* __restrict__ Wfrag, float* __restrict__ Wt,
                       float* __restrict__ Wxt, float* __restrict__ Wpt,
                       float* __restrict__ Woutt) {
  int blk = blockIdx.x, t = threadIdx.x;
  if (blk < 32) {
    int idx = blk * 256 + t;
    int L = idx & 63;
    int K = (idx >> 6) & 3;
    int T = idx >> 8;
    int n = 16 * T + (L & 15);
    int k0 = 32 * K + ((L >> 4) << 3);
    int g = n >> 7, o = n & 127;
    const float* U = (g == 0) ? Ui : (g == 1) ? Uo : (g == 2) ? Uu : Uf;
    unsigned short out[8];
    #pragma unroll
    for (int j = 0; j < 8; ++j) out[j] = f2bf(U[o * 128 + k0 + j]);
    *(int4*)(Wfrag + (size_t)idx * 8) = *(int4*)out;
  } else if (blk < 96) {
    bool isU = blk < 64;
    int base = (((blk & 31)) * 256 + t) * 8;
    int k = base >> 9;
    int col = base & 511;
    int gg = col >> 7, o0 = col & 127;
    const float* M;
    if (isU) M = (gg == 0) ? Ui : (gg == 1) ? Uo : (gg == 2) ? Uu : Uf;
    else     M = (gg == 0) ? Wi : (gg == 1) ? Wo : (gg == 2) ? Wu : Wf;
    float* D = isU ? Wt : Wxt;
    float v[8];
    #pragma unroll
    for (int j = 0; j < 8; ++j) v[j] = M[(o0 + j) * 128 + k];
    *(float4*)(D + base) = *(float4*)v;
    *(float4*)(D + base + 4) = *(float4*)(v + 4);
  } else if (blk == 96) {
    for (int i = t; i < E_ * H_; i += 256) {
      int e = i >> 7, o = i & 127;
      Wpt[i] = Wp[o * E_ + e];
    }
  } else {
    for (int i = t; i < H_ * H_; i += 256) {
      int k = i >> 7, o = i & 127;
      Woutt[i] = Wout[o * H_ + k];
    }
  }
}

// ---- pre1: leaf (blocks 0..20) + symx gate-interleaved (21..70) ----
__global__ void k_pre1(const float* __restrict__ emb, const float* __restrict__ sym_emb,
                       const float* __restrict__ Wpt, const float* __restrict__ Wxt,
                       const float* __restrict__ bp, const float* __restrict__ bi,
                       const float* __restrict__ bo, const float* __restrict__ bu,
                       const float* __restrict__ bfv,
                       unsigned short* __restrict__ leaf_h8, float* __restrict__ leaf_c,
                       float* __restrict__ symx) {
  int blk = blockIdx.x, t = threadIdx.x;
  __shared__ float x[128];
  if (blk < V_) {
    int v = blk;
    float acc = bp[t];
    if (v != 0) {  // reference zeroes emb row 0
      for (int e = 0; e < E_; ++e) acc = fmaf(emb[v * E_ + e], Wpt[e * 128 + t], acc);
    }
    x[t] = acc;
    __syncthreads();
    float zi = bi[t], zo = bo[t], zu = bu[t];
    for (int k = 0; k < H_; ++k) {
      float xv = x[k];
      const float* wr = Wxt + k * 512;
      zi = fmaf(xv, wr[t], zi);
      zo = fmaf(xv, wr[128 + t], zo);
      zu = fmaf(xv, wr[256 + t], zu);
    }
    float gi = sigm(zi), go = sigm(zo), gu = tanh_(zu);
    float c = gi * gu;
    leaf_c[v * H_ + t] = c;
    leaf_h8[v * H_ + t] = f2bf(go * tanh_(c));
  } else {
    int s = blk - V_;
    float acc = bp[t];
    for (int e = 0; e < E_; ++e) acc = fmaf(sym_emb[s * E_ + e], Wpt[e * 128 + t], acc);
    x[t] = acc;
    __syncthreads();
    float zi = bi[t], zo = bo[t], zu = bu[t], zf = bfv[t];
    for (int k = 0; k < H_; ++k) {
      float xv = x[k];
      const float* wr = Wxt + k * 512;
      zi = fmaf(xv, wr[t], zi);
      zo = fmaf(xv, wr[128 + t], zo);
      zu = fmaf(xv, wr[256 + t], zu);
      zf = fmaf(xv, wr[384 + t], zf);
    }
    float4 v4 = make_float4(zi, zo, zu, zf);
    *(float4*)(symx + (size_t)s * 512 + t * 4) = v4;
  }
}

// ---- table phase A: per-pair matvec pre-activations ----
__global__ void k_tabA(const unsigned short* __restrict__ leaf_h8, const float* __restrict__ Wt,
                       float* __restrict__ za) {
  int p = blockIdx.x, t = threadIdx.x;  // 441 x 128
  int tl = p / V_, tr = p % V_;
  __shared__ float hl[128], hr[128];
  hl[t] = bf2f(leaf_h8[tl * H_ + t]);
  hr[t] = bf2f(leaf_h8[tr * H_ + t]);
  __syncthreads();
  float zi = 0.f, zo = 0.f, zu = 0.f, pfl = 0.f, pfr = 0.f;
  for (int k = 0; k < H_; ++k) {
    float l = hl[k], r = hr[k], ht = l + r;
    const float* wr = Wt + k * 512;
    zi = fmaf(ht, wr[t], zi);
    zo = fmaf(ht, wr[128 + t], zo);
    zu = fmaf(ht, wr[256 + t], zu);
    float wf = wr[384 + t];
    pfl = fmaf(l, wf, pfl);
    pfr = fmaf(r, wf, pfr);
  }
  float* z = za + (size_t)p * 640;
  z[t] = zi; z[128 + t] = zo; z[256 + t] = zu; z[384 + t] = pfl; z[512 + t] = pfr;
}

// ---- table phase B: gate epilogue over 22050 rows + idx1 build ----
__global__ void k_tabB(const float* __restrict__ za, const float* __restrict__ symx,
                       const float* __restrict__ leaf_c,
                       const int* __restrict__ tokens, const int* __restrict__ symbols,
                       unsigned short* __restrict__ tab_h8, float* __restrict__ tab_c,
                       int* __restrict__ idx1) {
  int blk = blockIdx.x, t = threadIdx.x;
  if (blk < NTAB / 2) {
    int row = blk * 2 + (t >> 7);
    int u = t & 127;
    int p = row / S_, s = row - p * S_;
    int tl = p / V_, tr = p - tl * V_;
    const float* z = za + (size_t)p * 640;
    float4 sx = *(const float4*)(symx + (size_t)s * 512 + u * 4);
    Gates gt = gate_combine(sx, z[u], z[128 + u], z[256 + u], z[384 + u], z[512 + u],
                            leaf_c[tl * H_ + u], leaf_c[tr * H_ + u]);
    tab_c[(size_t)row * H_ + u] = gt.cv;
    tab_h8[(size_t)row * H_ + u] = f2bf(gt.hv);
  } else {
    int g = (blk - NTAB / 2) * 256 + t;
    int b = g >> 11, j = g & 2047;
    idx1[g] = (tokens[b * N_ + 2 * j] * V_ + tokens[b * N_ + 2 * j + 1]) * S_ + symbols[b * (N_ - 1) + j];
  }
}

// ---- fused levels 2+3 (gather from table), occupancy 4 ----
__global__ void __launch_bounds__(512, 4) k_lvl23(
    const unsigned short* __restrict__ Wfrag, const float* __restrict__ symx,
    const int* __restrict__ symbols, const int* __restrict__ idx1,
    const unsigned short* __restrict__ gh8, const float* __restrict__ gc,
    unsigned short* __restrict__ h_out8, float* __restrict__ c_out) {
  __shared__ __align__(16) unsigned short Ag[64][136];
  __shared__ __align__(16) unsigned short Bh[32][136];
  __shared__ float Bc[32][132];
  int t = threadIdx.x;
  int w = t >> 6, L = t & 63, q = L >> 4, cL = L & 15;
  int cc = 16 * w + cL;
  int g0 = blockIdx.x * 32;
  int b = g0 >> 10;
  int j2 = g0 & 1023;
  const int* sym_b = symbols + (size_t)b * (N_ - 1);
  const int* gix = idx1 + 2 * g0;

  #pragma unroll
  for (int i = 0; i < 2; ++i) {
    int fid = t + 512 * i;
    int row = fid >> 4, co = (fid & 15) * 8;
    *(int4*)&Ag[row][co] = *(const int4*)(gh8 + (size_t)gix[row] * H_ + co);
  }
  __syncthreads();

  const short8* wf = (const short8*)Wfrag;
  #pragma unroll
  for (int c = 0; c < 2; ++c) {
    float clp[4], crp[4];
    int spre[4];
    #pragma unroll
    for (int it = 0; it < 4; ++it) {
      int n = 16 * c + 8 * (it >> 1) + 2 * q + (it & 1);
      clp[it] = gc[(size_t)gix[2 * n] * H_ + cc];
      crp[it] = gc[(size_t)gix[2 * n + 1] * H_ + cc];
      spre[it] = sym_b[2048 + j2 + n];
    }
    f32x4 acc[2][4];
    #pragma unroll
    for (int r = 0; r < 2; ++r)
      #pragma unroll
      for (int g = 0; g < 4; ++g) acc[r][g] = (f32x4){0.f, 0.f, 0.f, 0.f};
    #pragma unroll
    for (int K = 0; K < 4; ++K) {
      short8 bfr[4];
      #pragma unroll
      for (int g = 0; g < 4; ++g) bfr[g] = wf[(size_t)((w + 8 * g) * 4 + K) * 64 + L];
      short8 a0 = *(const short8*)&Ag[32 * c + cL][K * 32 + q * 8];
      short8 a1 = *(const short8*)&Ag[32 * c + 16 + cL][K * 32 + q * 8];
      #pragma unroll
      for (int g = 0; g < 4; ++g) {
        acc[0][g] = __builtin_amdgcn_mfma_f32_16x16x32_bf16(a0, bfr[g], acc[0][g], 0, 0, 0);
        acc[1][g] = __builtin_amdgcn_mfma_f32_16x16x32_bf16(a1, bfr[g], acc[1][g], 0, 0, 0);
      }
    }
    #pragma unroll
    for (int r = 0; r < 2; ++r) {
      #pragma unroll
      for (int nd = 0; nd < 2; ++nd) {
        int it = r * 2 + nd;
        int n = 16 * c + 8 * r + 2 * q + nd;
        float4 sx = *(const float4*)(symx + (size_t)spre[it] * 512 + cc * 4);
        Gates gt = gate_combine(sx,
            acc[r][0][2 * nd] + acc[r][0][2 * nd + 1],
            acc[r][1][2 * nd] + acc[r][1][2 * nd + 1],
            acc[r][2][2 * nd] + acc[r][2][2 * nd + 1],
            acc[r][3][2 * nd], acc[r][3][2 * nd + 1], clp[it], crp[it]);
        Bc[n][cc] = gt.cv;
        Bh[n][cc] = f2bf(gt.hv);
      }
    }
  }
  __syncthreads();
  {
    int spre[4];
    #pragma unroll
    for (int it = 0; it < 4; ++it) {
      int n = 8 * (it >> 1) + 2 * q + (it & 1);
      spre[it] = sym_b[3072 + (j2 >> 1) + n];
    }
    f32x4 acc[2][4];
    #pragma unroll
    for (int r = 0; r < 2; ++r)
      #pragma unroll
      for (int g = 0; g < 4; ++g) acc[r][g] = (f32x4){0.f, 0.f, 0.f, 0.f};
    #pragma unroll
    for (int K = 0; K < 4; ++K) {
      short8 bfr[4];
      #pragma unroll
      for (int g = 0; g < 4; ++g) bfr[g] = wf[(size_t)((w + 8 * g) * 4 + K) * 64 + L];
      short8 a0 = *(const short8*)&Bh[cL][K * 32 + q * 8];
      short8 a1 = *(const short8*)&Bh[16 + cL][K * 32 + q * 8];
      #pragma unroll
      for (int g = 0; g < 4; ++g) {
        acc[0][g] = __builtin_amdgcn_mfma_f32_16x16x32_bf16(a0, bfr[g], acc[0][g], 0, 0, 0);
        acc[1][g] = __builtin_amdgcn_mfma_f32_16x16x32_bf16(a1, bfr[g], acc[1][g], 0, 0, 0);
      }
    }
    #pragma unroll
    for (int r = 0; r < 2; ++r) {
      #pragma unroll
      for (int nd = 0; nd < 2; ++nd) {
        int it = r * 2 + nd;
        int n = 8 * r + 2 * q + nd;
        int G3 = (g0 >> 1) + n;
        float4 sx = *(const float4*)(symx + (size_t)spre[it] * 512 + cc * 4);
        Gates gt = gate_combine(sx,
            acc[r][0][2 * nd] + acc[r][0][2 * nd + 1],
            acc[r][1][2 * nd] + acc[r][1][2 * nd + 1],
            acc[r][2][2 * nd] + acc[r][2][2 * nd + 1],
            acc[r][3][2 * nd], acc[r][3][2 * nd + 1],
            Bc[2 * n][cc], Bc[2 * n + 1][cc]);
        c_out[(size_t)G3 * H_ + cc] = gt.cv;
        h_out8[(size_t)G3 * H_ + cc] = f2bf(gt.hv);
      }
    }
  }
}

// ---- k_mid: levels 4-9 fused; 512 blocks, subtree-local, LDS ping-pong ----
// Block blk: 32 L4 nodes (batch b=blk>>3, subtree sub=blk&7) -> ... -> 1 L9 node.
__global__ void __launch_bounds__(512, 2) k_mid(
    const unsigned short* __restrict__ Wfrag, const float* __restrict__ symx,
    const int* __restrict__ symbols,
    const unsigned short* __restrict__ in_h8, const float* __restrict__ in_c,
    unsigned short* __restrict__ out_h8, float* __restrict__ out_c) {
  __shared__ __align__(16) unsigned short Ah0[64][136];
  __shared__ __align__(16) unsigned short Ah1[32][136];
  __shared__ float Cs0[64][128];
  __shared__ float Cs1[32][128];
  int t = threadIdx.x;
  int w = t >> 6, L = t & 63, q = L >> 4, cL = L & 15;
  int cc = 16 * w + cL;
  int blk = blockIdx.x;
  int b = blk >> 3, sub = blk & 7;
  size_t base3 = (size_t)blk * 64;  // first L3 child row

  #pragma unroll
  for (int i = 0; i < 2; ++i) {
    int fid = t + 512 * i;
    int row = fid >> 4, co = (fid & 15) * 8;
    *(int4*)&Ah0[row][co] = *(const int4*)(in_h8 + (base3 + row) * H_ + co);
  }
  #pragma unroll
  for (int i = 0; i < 4; ++i) {
    int fid = t + 512 * i;
    int row = fid >> 5, c4 = (fid & 31) << 2;
    *(float4*)&Cs0[row][c4] = *(const float4*)(in_c + (base3 + row) * H_ + c4);
  }
  __syncthreads();

  const short8* wf = (const short8*)Wfrag;
  int R = 64;
  #pragma unroll
  for (int lev = 0; lev < 6; ++lev) {
    const int l = 4 + lev;
    const int nodes = R >> 1;
    const int jb = b * (N_ - 1) + (N_ - (N_ >> (l - 1))) + ((sub * 32) >> lev);
    unsigned short (*Ard)[136] = (lev & 1) ? Ah1 : Ah0;
    unsigned short (*Awr)[136] = (lev & 1) ? Ah0 : Ah1;
    const float* crd = (lev & 1) ? &Cs1[0][0] : &Cs0[0][0];
    float* cwr = (lev & 1) ? &Cs0[0][0] : &Cs1[0][0];
    const int nchunk = (nodes + 15) >> 4;
    for (int c = 0; c < nchunk; ++c) {
      int spre[4];
      #pragma unroll
      for (int it = 0; it < 4; ++it) {
        int n = 16 * c + 8 * (it >> 1) + 2 * q + (it & 1);
        spre[it] = (n < nodes) ? symbols[jb + n] : 0;
      }
      f32x4 acc[2][4];
      #pragma unroll
      for (int r = 0; r < 2; ++r)
        #pragma unroll
        for (int g = 0; g < 4; ++g) acc[r][g] = (f32x4){0.f, 0.f, 0.f, 0.f};
      const bool useA1 = (2 * nodes - 32 * c) > 16;
      #pragma unroll
      for (int K = 0; K < 4; ++K) {
        short8 bfr[4];
        #pragma unroll
        for (int g = 0; g < 4; ++g) bfr[g] = wf[(size_t)((w + 8 * g) * 4 + K) * 64 + L];
        short8 a0 = *(const short8*)&Ard[32 * c + cL][K * 32 + q * 8];
        #pragma unroll
        for (int g = 0; g < 4; ++g)
          acc[0][g] = __builtin_amdgcn_mfma_f32_16x16x32_bf16(a0, bfr[g], acc[0][g], 0, 0, 0);
        if (useA1) {
          short8 a1 = *(const short8*)&Ard[32 * c + 16 + cL][K * 32 + q * 8];
          #pragma unroll
          for (int g = 0; g < 4; ++g)
            acc[1][g] = __builtin_amdgcn_mfma_f32_16x16x32_bf16(a1, bfr[g], acc[1][g], 0, 0, 0);
        }
      }
      #pragma unroll
      for (int r = 0; r < 2; ++r) {
        #pragma unroll
        for (int nd = 0; nd < 2; ++nd) {
          int it = r * 2 + nd;
          int n = 16 * c + 8 * r + 2 * q + nd;
          if (n < nodes) {
            float4 sx = *(const float4*)(symx + (size_t)spre[it] * 512 + cc * 4);
            Gates gt = gate_combine(sx,
                acc[r][0][2 * nd] + acc[r][0][2 * nd + 1],
                acc[r][1][2 * nd] + acc[r][1][2 * nd + 1],
                acc[r][2][2 * nd] + acc[r][2][2 * nd + 1],
                acc[r][3][2 * nd], acc[r][3][2 * nd + 1],
                crd[(size_t)(2 * n) * 128 + cc], crd[(size_t)(2 * n + 1) * 128 + cc]);
            if (lev == 5) {
              out_c[(size_t)blk * H_ + cc] = gt.cv;
              out_h8[(size_t)blk * H_ + cc] = f2bf(gt.hv);
            } else {
              cwr[(size_t)n * 128 + cc] = gt.cv;
              Awr[n][cc] = f2bf(gt.hv);
            }
          }
        }
      }
    }
    __syncthreads();
    R >>= 1;
  }
}

// ---- k_fin: levels 10-12 + fused projection; 64 blocks ----
__global__ void __launch_bounds__(512, 2) k_fin(
    const unsigned short* __restrict__ Wfrag, const float* __restrict__ symx,
    const int* __restrict__ symbols,
    const unsigned short* __restrict__ in_h8, const float* __restrict__ in_c,
    const float* __restrict__ Woutt, const float* __restrict__ bout,
    float* __restrict__ out) {
  __shared__ __align__(16) unsigned short Ah0[8][136];
  __shared__ __align__(16) unsigned short Ah1[4][136];
  __shared__ float Cs0[8][128];
  __shared__ float Cs1[4][128];
  __shared__ float rootv[128];
  int t = threadIdx.x;
  int w = t >> 6, L = t & 63, q = L >> 4, cL = L & 15;
  int cc = 16 * w + cL;
  int b = blockIdx.x;

  if (t < 128) {  // 8 rows x 16 int4
    int row = t >> 4, co = (t & 15) * 8;
    *(int4*)&Ah0[row][co] = *(const int4*)(in_h8 + (size_t)(b * 8 + row) * H_ + co);
  }
  if (t < 256) {  // 8 rows x 32 float4
    int row = t >> 5, c4 = (t & 31) << 2;
    *(float4*)&Cs0[row][c4] = *(const float4*)(in_c + (size_t)(b * 8 + row) * H_ + c4);
  }
  __syncthreads();

  const short8* wf = (const short8*)Wfrag;
  int R = 8;
  #pragma unroll
  for (int lev = 0; lev < 3; ++lev) {
    const int l = 10 + lev;
    const int nodes = R >> 1;
    const int jb = b * (N_ - 1) + (N_ - (N_ >> (l - 1)));
    unsigned short (*Ard)[136] = (lev & 1) ? Ah1 : Ah0;
    unsigned short (*Awr)[136] = (lev & 1) ? Ah0 : Ah1;
    const float* crd = (lev & 1) ? &Cs1[0][0] : &Cs0[0][0];
    float* cwr = (lev & 1) ? &Cs0[0][0] : &Cs1[0][0];
    int spre[4];
    #pragma unroll
    for (int it = 0; it < 4; ++it) {
      int n = 8 * (it >> 1) + 2 * q + (it & 1);
      spre[it] = (n < nodes) ? symbols[jb + n] : 0;
    }
    f32x4 acc[4];
    #pragma unroll
    for (int g = 0; g < 4; ++g) acc[g] = (f32x4){0.f, 0.f, 0.f, 0.f};
    #pragma unroll
    for (int K = 0; K < 4; ++K) {
      short8 bfr[4];
      #pragma unroll
      for (int g = 0; g < 4; ++g) bfr[g] = wf[(size_t)((w + 8 * g) * 4 + K) * 64 + L];
      // rows = 2*nodes <= 8: a0 only; rows beyond hold stale-but-finite data
      short8 a0 = *(const short8*)&Ard[cL & 7][K * 32 + q * 8];
      // note: cL in [0,16): rows 8..15 of the 16x16 A-tile must read *some* valid LDS
      // Ard has only 8 rows for lev=0; mask cL to stay in-bounds (results unused).
      #pragma unroll
      for (int g = 0; g < 4; ++g)
        acc[g] = __builtin_amdgcn_mfma_f32_16x16x32_bf16(a0, bfr[g], acc[g], 0, 0, 0);
    }
    #pragma unroll
    for (int nd = 0; nd < 2; ++nd) {
      int it = nd;  // r==0
      int n = 2 * q + nd;
      if (n < nodes) {
        float4 sx = *(const float4*)(symx + (size_t)spre[it] * 512 + cc * 4);
        Gates gt = gate_combine(sx,
            acc[0][2 * nd] + acc[0][2 * nd + 1],
            acc[1][2 * nd] + acc[1][2 * nd + 1],
            acc[2][2 * nd] + acc[2][2 * nd + 1],
            acc[3][2 * nd], acc[3][2 * nd + 1],
            crd[(size_t)(2 * n) * 128 + cc], crd[(size_t)(2 * n + 1) * 128 + cc]);
        if (lev == 2) {
          rootv[cc] = gt.hv;
        } else {
          cwr[(size_t)n * 128 + cc] = gt.cv;
          Awr[n][cc] = f2bf(gt.hv);
        }
      }
    }
    __syncthreads();
    R >>= 1;
  }
  // fused projection: out[b] = rootv @ Woutt + bout
  if (t < 128) {
    float acc = bout[t];
    for (int k = 0; k < H_; ++k) acc = fmaf(rootv[k], Woutt[k * 128 + t], acc);
    out[(size_t)b * H_ + t] = acc;
  }
}

extern "C" void kernel_launch(void* const* d_in, const int* in_sizes, int n_in,
                              void* d_out, int out_size, void* d_ws, size_t ws_size,
                              hipStream_t stream) {
  const int* tokens    = (const int*)d_in[0];
  const int* symbols   = (const int*)d_in[1];
  const float* emb     = (const float*)d_in[2];
  const float* sym_emb = (const float*)d_in[3];
  const float* Wp  = (const float*)d_in[4];
  const float* bp  = (const float*)d_in[5];
  const float* Wi  = (const float*)d_in[6];
  const float* bi  = (const float*)d_in[7];
  const float* Ui  = (const float*)d_in[8];
  const float* Wf  = (const float*)d_in[9];
  const float* bf  = (const float*)d_in[10];
  const float* Uf  = (const float*)d_in[11];
  const float* Wo  = (const float*)d_in[12];
  const float* bo  = (const float*)d_in[13];
  const float* Uo  = (const float*)d_in[14];
  const float* Wu  = (const float*)d_in[15];
  const float* bu  = (const float*)d_in[16];
  const float* Uu  = (const float*)d_in[17];
  const float* Wout= (const float*)d_in[18];
  const float* bout= (const float*)d_in[19];

  // Workspace layout (~45 MB)
  char* ws = (char*)d_ws;
  unsigned short* Wfrag   = (unsigned short*)(ws);                  // 131072
  float*          Wt      = (float*)(ws + 131072);                  // 262144
  float*          Wxt     = (float*)(ws + 393216);                  // 262144
  float*          Wpt     = (float*)(ws + 655360);                  // 32768
  float*          Woutt   = (float*)(ws + 688128);                  // 65536
  unsigned short* leaf_h8 = (unsigned short*)(ws + 753664);         // 5376
  float*          leaf_c  = (float*)(ws + 759040);                  // 10752
  float*          symx    = (float*)(ws + 769792);                  // 102400
  float*          za      = (float*)(ws + 872192);                  // 1128960
  unsigned short* tab_h8  = (unsigned short*)(ws + 2001152UL);      // 5644800
  float*          tab_c   = (float*)(ws + 7645952UL);               // 11289600
  int*            idx1    = (int*)(ws + 18935552UL);                // 524288
  unsigned short* L3h8    = (unsigned short*)(ws + 19459840UL);     // 32768*128*2 = 8388608
  float*          L3c     = (float*)(ws + 27848448UL);              // 32768*128*4 = 16777216
  unsigned short* L9h8    = (unsigned short*)(ws + 44625664UL);     // 512*128*2 = 131072
  float*          L9c     = (float*)(ws + 44756736UL);              // 512*128*4 = 262144

  k_pre0<<<98, 256, 0, stream>>>(Ui, Uo, Uu, Uf, Wi, Wo, Wu, Wf, Wp, Wout,
                                 Wfrag, Wt, Wxt, Wpt, Woutt);
  k_pre1<<<V_ + S_, 128, 0, stream>>>(emb, sym_emb, Wpt, Wxt,
                                      bp, bi, bo, bu, bf, leaf_h8, leaf_c, symx);
  k_tabA<<<NPAIR, 128, 0, stream>>>(leaf_h8, Wt, za);
  k_tabB<<<NTAB / 2 + 512, 256, 0, stream>>>(za, symx, leaf_c, tokens, symbols,
                                             tab_h8, tab_c, idx1);
  k_lvl23<<<2048, 512, 0, stream>>>(Wfrag, symx, symbols, idx1, tab_h8, tab_c, L3h8, L3c);
  k_mid<<<512, 512, 0, stream>>>(Wfrag, symx, symbols, L3h8, L3c, L9h8, L9c);
  k_fin<<<B_, 512, 0, stream>>>(Wfrag, symx, symbols, L9h8, L9c, Woutt, bout,
                                (float*)d_out);
}

// Round 10
// 216.214 us; speedup vs baseline: 1.1122x; 1.0252x over previous
//
#include <hip/hip_runtime.h>
#include <hip/hip_bf16.h>

typedef __attribute__((ext_vector_type(8))) short short8;
typedef __attribute__((ext_vector_type(4))) float f32x4;

static constexpr int B_ = 64;
static constexpr int N_ = 4096;
static constexpr int V_ = 21;
static constexpr int S_ = 50;
static constexpr int E_ = 64;
static constexpr int H_ = 128;
static constexpr int NPAIR = V_ * V_;   // 441
static constexpr int NTAB = NPAIR * S_; // 22050

__device__ __forceinline__ float rcp_(float x) { return __builtin_amdgcn_rcpf(x); }
__device__ __forceinline__ float sigm(float x) { return rcp_(1.0f + __expf(-x)); }
__device__ __forceinline__ float tanh_(float x) {
  float a = fabsf(x);
  float e = __expf(-2.0f * a);
  float t = (1.0f - e) * rcp_(1.0f + e);
  return x < 0.0f ? -t : t;
}
__device__ __forceinline__ unsigned short f2bf(float f) {
  __hip_bfloat16 b = __float2bfloat16(f);
  return *reinterpret_cast<unsigned short*>(&b);
}
__device__ __forceinline__ float bf2f(unsigned short u) {
  return __uint_as_float(((unsigned int)u) << 16);
}

struct Gates { float cv, hv; };
// sx: gate-interleaved symx entry for this (s, cc): {i, o, u, f}
__device__ __forceinline__ Gates gate_combine(float4 sx,
    float i_p, float o_p, float u_p, float fl_p, float fr_p, float cl, float cr) {
  float gi = sigm(sx.x + i_p);
  float go = sigm(sx.y + o_p);
  float gu = tanh_(sx.z + u_p);
  float fl = sigm(sx.w + fl_p);
  float fr = sigm(sx.w + fr_p);
  float cv = fmaf(gi, gu, fmaf(fl, cl, fr * cr));
  Gates g; g.cv = cv; g.hv = go * tanh_(cv);
  return g;
}

// ---- pre0: weight transposes, fully coalesced via LDS tiles ----
// blocks 0..15: Wfrag; 16..47: LDS-transpose jobs (8 matrices x 4 k-tiles) -> Wt/Wxt;
// 48: Wpt; 49: Woutt.
__global__ void __launch_bounds__(512) k_pre0(
    const float* __restrict__ Ui, const float* __restrict__ Uo,
    const float* __restrict__ Uu, const float* __restrict__ Uf,
    const float* __restrict__ Wi, const float* __restrict__ Wo,
    const float* __restrict__ Wu, const float* __restrict__ Wf,
    const float* __restrict__ Wp, const float* __restrict__ Wout,
    unsigned short* __restrict__ Wfrag, float* __restrict__ Wt,
    float* __restrict__ Wxt, float* __restrict__ Wpt,
    float* __restrict__ Woutt) {
  __shared__ float Tt[32][129];
  int blk = blockIdx.x, t = threadIdx.x;
  if (blk < 16) {
    int idx = blk * 512 + t;  // 8192 frag entries
    int L = idx & 63;
    int K = (idx >> 6) & 3;
    int T = idx >> 8;
    int n = 16 * T + (L & 15);
    int k0 = 32 * K + ((L >> 4) << 3);
    int g = n >> 7, o = n & 127;
    const float* U = (g == 0) ? Ui : (g == 1) ? Uo : (g == 2) ? Uu : Uf;
    unsigned short out[8];
    #pragma unroll
    for (int j = 0; j < 8; ++j) out[j] = f2bf(U[o * 128 + k0 + j]);
    *(int4*)(Wfrag + (size_t)idx * 8) = *(int4*)out;
  } else if (blk < 48) {
    int job = blk - 16;            // 0..31
    int m = job >> 2, kt = job & 3;
    int k0 = kt * 32;
    const float* M = (m == 0) ? Ui : (m == 1) ? Uo : (m == 2) ? Uu : (m == 3) ? Uf
                   : (m == 4) ? Wi : (m == 5) ? Wo : (m == 6) ? Wu : Wf;
    float* D = (m < 4) ? Wt : Wxt;
    int g = m & 3;
    #pragma unroll
    for (int pass = 0; pass < 2; ++pass) {
      int o = (t >> 3) + 64 * pass;
      int kk = 4 * (t & 7);
      float4 v = *(const float4*)(M + o * 128 + k0 + kk);
      Tt[kk][o] = v.x; Tt[kk + 1][o] = v.y; Tt[kk + 2][o] = v.z; Tt[kk + 3][o] = v.w;
    }
    __syncthreads();
    #pragma unroll
    for (int pass = 0; pass < 8; ++pass) {
      int kk = pass * 4 + (t >> 7);
      int o = t & 127;
      D[(size_t)(k0 + kk) * 512 + g * 128 + o] = Tt[kk][o];
    }
  } else if (blk == 48) {
    for (int i = t; i < E_ * H_; i += 512) {
      int e = i >> 7, o = i & 127;
      Wpt[i] = Wp[o * E_ + e];
    }
  } else {
    for (int i = t; i < H_ * H_; i += 512) {
      int k = i >> 7, o = i & 127;
      Woutt[i] = Wout[o * H_ + k];
    }
  }
}

// ---- pre1: leaf tables + P_leaf (blocks 0..20), symx gate-interleaved (21..70) ----
// 512 threads; one output column per thread in each matvec phase.
__global__ void __launch_bounds__(512) k_pre1(
    const float* __restrict__ emb, const float* __restrict__ sym_emb,
    const float* __restrict__ Wpt, const float* __restrict__ Wxt,
    const float* __restrict__ Wt,
    const float* __restrict__ bp, const float* __restrict__ bi,
    const float* __restrict__ bo, const float* __restrict__ bu,
    const float* __restrict__ bfv,
    unsigned short* __restrict__ leaf_h8, float* __restrict__ leaf_c,
    float* __restrict__ symx, float* __restrict__ P_leaf) {
  __shared__ float x[128];
  __shared__ float zs[512];
  __shared__ float hl[128];
  int blk = blockIdx.x, t = threadIdx.x;
  if (blk < V_) {
    int v = blk;
    if (t < 128) {
      float acc = bp[t];
      if (v != 0) {  // reference zeroes emb row 0
        for (int e = 0; e < E_; ++e) acc = fmaf(emb[v * E_ + e], Wpt[e * 128 + t], acc);
      }
      x[t] = acc;
    }
    __syncthreads();
    if (t < 384) {  // cols 0..383 = i|o|u
      int g = t >> 7;
      const float* bb = (g == 0) ? bi : (g == 1) ? bo : bu;
      float z = bb[t & 127];
      for (int k = 0; k < H_; ++k) z = fmaf(x[k], Wxt[k * 512 + t], z);
      zs[t] = z;
    }
    __syncthreads();
    if (t < 128) {
      float gi = sigm(zs[t]), go = sigm(zs[128 + t]), gu = tanh_(zs[256 + t]);
      float c = gi * gu;
      leaf_c[v * H_ + t] = c;
      unsigned short hb = f2bf(go * tanh_(c));
      leaf_h8[v * H_ + t] = hb;
      hl[t] = bf2f(hb);
    }
    __syncthreads();
    {  // P_leaf row v: bf16-rounded h x fp32 U, all 512 cols
      float z = 0.f;
      for (int k = 0; k < H_; ++k) z = fmaf(hl[k], Wt[k * 512 + t], z);
      P_leaf[(size_t)v * 512 + t] = z;
    }
  } else {
    int s = blk - V_;
    if (t < 128) {
      float acc = bp[t];
      for (int e = 0; e < E_; ++e) acc = fmaf(sym_emb[s * E_ + e], Wpt[e * 128 + t], acc);
      x[t] = acc;
    }
    __syncthreads();
    {
      int g = t >> 7;
      const float* bb = (g == 0) ? bi : (g == 1) ? bo : (g == 2) ? bu : bfv;
      float z = bb[t & 127];
      for (int k = 0; k < H_; ++k) z = fmaf(x[k], Wxt[k * 512 + t], z);
      zs[t] = z;
    }
    __syncthreads();
    if (t < 128) {
      float4 v4 = make_float4(zs[t], zs[128 + t], zs[256 + t], zs[384 + t]);
      *(float4*)(symx + (size_t)s * 512 + t * 4) = v4;
    }
  }
}

// ---- tabB: gate epilogue over 22050 rows (gathering from P_leaf) + idx1 build ----
__global__ void k_tabB(const float* __restrict__ P_leaf, const float* __restrict__ symx,
                       const float* __restrict__ leaf_c,
                       const int* __restrict__ tokens, const int* __restrict__ symbols,
                       unsigned short* __restrict__ tab_h8, float* __restrict__ tab_c,
                       int* __restrict__ idx1) {
  int blk = blockIdx.x, t = threadIdx.x;
  if (blk < NTAB / 2) {
    int row = blk * 2 + (t >> 7);
    int u = t & 127;
    int p = row / S_, s = row - p * S_;
    int tl = p / V_, tr = p - tl * V_;
    const float* Pl = P_leaf + (size_t)tl * 512;
    const float* Pr = P_leaf + (size_t)tr * 512;
    float4 sx = *(const float4*)(symx + (size_t)s * 512 + u * 4);
    Gates gt = gate_combine(sx,
        Pl[u] + Pr[u], Pl[128 + u] + Pr[128 + u], Pl[256 + u] + Pr[256 + u],
        Pl[384 + u], Pr[384 + u],
        leaf_c[tl * H_ + u], leaf_c[tr * H_ + u]);
    tab_c[(size_t)row * H_ + u] = gt.cv;
    tab_h8[(size_t)row * H_ + u] = f2bf(gt.hv);
  } else {
    int g = (blk - NTAB / 2) * 256 + t;
    int b = g >> 11, j = g & 2047;
    idx1[g] = (tokens[b * N_ + 2 * j] * V_ + tokens[b * N_ + 2 * j + 1]) * S_ + symbols[b * (N_ - 1) + j];
  }
}

// ---- fused levels 2+3 (gather from table), occupancy 4 ----
__global__ void __launch_bounds__(512, 4) k_lvl23(
    const unsigned short* __restrict__ Wfrag, const float* __restrict__ symx,
    const int* __restrict__ symbols, const int* __restrict__ idx1,
    const unsigned short* __restrict__ gh8, const float* __restrict__ gc,
    unsigned short* __restrict__ h_out8, float* __restrict__ c_out) {
  __shared__ __align__(16) unsigned short Ag[64][136];
  __shared__ __align__(16) unsigned short Bh[32][136];
  __shared__ float Bc[32][132];
  int t = threadIdx.x;
  int w = t >> 6, L = t & 63, q = L >> 4, cL = L & 15;
  int cc = 16 * w + cL;
  int g0 = blockIdx.x * 32;
  int b = g0 >> 10;
  int j2 = g0 & 1023;
  const int* sym_b = symbols + (size_t)b * (N_ - 1);
  const int* gix = idx1 + 2 * g0;

  #pragma unroll
  for (int i = 0; i < 2; ++i) {
    int fid = t + 512 * i;
    int row = fid >> 4, co = (fid & 15) * 8;
    *(int4*)&Ag[row][co] = *(const int4*)(gh8 + (size_t)gix[row] * H_ + co);
  }
  __syncthreads();

  const short8* wf = (const short8*)Wfrag;
  #pragma unroll
  for (int c = 0; c < 2; ++c) {
    float clp[4], crp[4];
    int spre[4];
    #pragma unroll
    for (int it = 0; it < 4; ++it) {
      int n = 16 * c + 8 * (it >> 1) + 2 * q + (it & 1);
      clp[it] = gc[(size_t)gix[2 * n] * H_ + cc];
      crp[it] = gc[(size_t)gix[2 * n + 1] * H_ + cc];
      spre[it] = sym_b[2048 + j2 + n];
    }
    f32x4 acc[2][4];
    #pragma unroll
    for (int r = 0; r < 2; ++r)
      #pragma unroll
      for (int g = 0; g < 4; ++g) acc[r][g] = (f32x4){0.f, 0.f, 0.f, 0.f};
    #pragma unroll
    for (int K = 0; K < 4; ++K) {
      short8 bfr[4];
      #pragma unroll
      for (int g = 0; g < 4; ++g) bfr[g] = wf[(size_t)((w + 8 * g) * 4 + K) * 64 + L];
      short8 a0 = *(const short8*)&Ag[32 * c + cL][K * 32 + q * 8];
      short8 a1 = *(const short8*)&Ag[32 * c + 16 + cL][K * 32 + q * 8];
      #pragma unroll
      for (int g = 0; g < 4; ++g) {
        acc[0][g] = __builtin_amdgcn_mfma_f32_16x16x32_bf16(a0, bfr[g], acc[0][g], 0, 0, 0);
        acc[1][g] = __builtin_amdgcn_mfma_f32_16x16x32_bf16(a1, bfr[g], acc[1][g], 0, 0, 0);
      }
    }
    #pragma unroll
    for (int r = 0; r < 2; ++r) {
      #pragma unroll
      for (int nd = 0; nd < 2; ++nd) {
        int it = r * 2 + nd;
        int n = 16 * c + 8 * r + 2 * q + nd;
        float4 sx = *(const float4*)(symx + (size_t)spre[it] * 512 + cc * 4);
        Gates gt = gate_combine(sx,
            acc[r][0][2 * nd] + acc[r][0][2 * nd + 1],
            acc[r][1][2 * nd] + acc[r][1][2 * nd + 1],
            acc[r][2][2 * nd] + acc[r][2][2 * nd + 1],
            acc[r][3][2 * nd], acc[r][3][2 * nd + 1], clp[it], crp[it]);
        Bc[n][cc] = gt.cv;
        Bh[n][cc] = f2bf(gt.hv);
      }
    }
  }
  __syncthreads();
  {
    int spre[4];
    #pragma unroll
    for (int it = 0; it < 4; ++it) {
      int n = 8 * (it >> 1) + 2 * q + (it & 1);
      spre[it] = sym_b[3072 + (j2 >> 1) + n];
    }
    f32x4 acc[2][4];
    #pragma unroll
    for (int r = 0; r < 2; ++r)
      #pragma unroll
      for (int g = 0; g < 4; ++g) acc[r][g] = (f32x4){0.f, 0.f, 0.f, 0.f};
    #pragma unroll
    for (int K = 0; K < 4; ++K) {
      short8 bfr[4];
      #pragma unroll
      for (int g = 0; g < 4; ++g) bfr[g] = wf[(size_t)((w + 8 * g) * 4 + K) * 64 + L];
      short8 a0 = *(const short8*)&Bh[cL][K * 32 + q * 8];
      short8 a1 = *(const short8*)&Bh[16 + cL][K * 32 + q * 8];
      #pragma unroll
      for (int g = 0; g < 4; ++g) {
        acc[0][g] = __builtin_amdgcn_mfma_f32_16x16x32_bf16(a0, bfr[g], acc[0][g], 0, 0, 0);
        acc[1][g] = __builtin_amdgcn_mfma_f32_16x16x32_bf16(a1, bfr[g], acc[1][g], 0, 0, 0);
      }
    }
    #pragma unroll
    for (int r = 0; r < 2; ++r) {
      #pragma unroll
      for (int nd = 0; nd < 2; ++nd) {
        int it = r * 2 + nd;
        int n = 8 * r + 2 * q + nd;
        int G3 = (g0 >> 1) + n;
        float4 sx = *(const float4*)(symx + (size_t)spre[it] * 512 + cc * 4);
        Gates gt = gate_combine(sx,
            acc[r][0][2 * nd] + acc[r][0][2 * nd + 1],
            acc[r][1][2 * nd] + acc[r][1][2 * nd + 1],
            acc[r][2][2 * nd] + acc[r][2][2 * nd + 1],
            acc[r][3][2 * nd], acc[r][3][2 * nd + 1],
            Bc[2 * n][cc], Bc[2 * n + 1][cc]);
        c_out[(size_t)G3 * H_ + cc] = gt.cv;
        h_out8[(size_t)G3 * H_ + cc] = f2bf(gt.hv);
      }
    }
  }
}

// ---- k_mid: levels 4-9 fused; 512 blocks, subtree-local, LDS ping-pong ----
__global__ void __launch_bounds__(512, 2) k_mid(
    const unsigned short* __restrict__ Wfrag, const float* __restrict__ symx,
    const int* __restrict__ symbols,
    const unsigned short* __restrict__ in_h8, const float* __restrict__ in_c,
    unsigned short* __restrict__ out_h8, float* __restrict__ out_c) {
  __shared__ __align__(16) unsigned short Ah0[64][136];
  __shared__ __align__(16) unsigned short Ah1[32][136];
  __shared__ float Cs0[64][128];
  __shared__ float Cs1[32][128];
  int t = threadIdx.x;
  int w = t >> 6, L = t & 63, q = L >> 4, cL = L & 15;
  int cc = 16 * w + cL;
  int blk = blockIdx.x;
  int b = blk >> 3, sub = blk & 7;
  size_t base3 = (size_t)blk * 64;

  #pragma unroll
  for (int i = 0; i < 2; ++i) {
    int fid = t + 512 * i;
    int row = fid >> 4, co = (fid & 15) * 8;
    *(int4*)&Ah0[row][co] = *(const int4*)(in_h8 + (base3 + row) * H_ + co);
  }
  #pragma unroll
  for (int i = 0; i < 4; ++i) {
    int fid = t + 512 * i;
    int row = fid >> 5, c4 = (fid & 31) << 2;
    *(float4*)&Cs0[row][c4] = *(const float4*)(in_c + (base3 + row) * H_ + c4);
  }
  __syncthreads();

  const short8* wf = (const short8*)Wfrag;
  int R = 64;
  #pragma unroll
  for (int lev = 0; lev < 6; ++lev) {
    const int l = 4 + lev;
    const int nodes = R >> 1;
    const int jb = b * (N_ - 1) + (N_ - (N_ >> (l - 1))) + ((sub * 32) >> lev);
    unsigned short (*Ard)[136] = (lev & 1) ? Ah1 : Ah0;
    unsigned short (*Awr)[136] = (lev & 1) ? Ah0 : Ah1;
    const float* crd = (lev & 1) ? &Cs1[0][0] : &Cs0[0][0];
    float* cwr = (lev & 1) ? &Cs0[0][0] : &Cs1[0][0];
    const int nchunk = (nodes + 15) >> 4;
    for (int c = 0; c < nchunk; ++c) {
      int spre[4];
      #pragma unroll
      for (int it = 0; it < 4; ++it) {
        int n = 16 * c + 8 * (it >> 1) + 2 * q + (it & 1);
        spre[it] = (n < nodes) ? symbols[jb + n] : 0;
      }
      f32x4 acc[2][4];
      #pragma unroll
      for (int r = 0; r < 2; ++r)
        #pragma unroll
        for (int g = 0; g < 4; ++g) acc[r][g] = (f32x4){0.f, 0.f, 0.f, 0.f};
      const bool useA1 = (2 * nodes - 32 * c) > 16;
      #pragma unroll
      for (int K = 0; K < 4; ++K) {
        short8 bfr[4];
        #pragma unroll
        for (int g = 0; g < 4; ++g) bfr[g] = wf[(size_t)((w + 8 * g) * 4 + K) * 64 + L];
        short8 a0 = *(const short8*)&Ard[32 * c + cL][K * 32 + q * 8];
        #pragma unroll
        for (int g = 0; g < 4; ++g)
          acc[0][g] = __builtin_amdgcn_mfma_f32_16x16x32_bf16(a0, bfr[g], acc[0][g], 0, 0, 0);
        if (useA1) {
          short8 a1 = *(const short8*)&Ard[32 * c + 16 + cL][K * 32 + q * 8];
          #pragma unroll
          for (int g = 0; g < 4; ++g)
            acc[1][g] = __builtin_amdgcn_mfma_f32_16x16x32_bf16(a1, bfr[g], acc[1][g], 0, 0, 0);
        }
      }
      #pragma unroll
      for (int r = 0; r < 2; ++r) {
        #pragma unroll
        for (int nd = 0; nd < 2; ++nd) {
          int it = r * 2 + nd;
          int n = 16 * c + 8 * r + 2 * q + nd;
          if (n < nodes) {
            float4 sx = *(const float4*)(symx + (size_t)spre[it] * 512 + cc * 4);
            Gates gt = gate_combine(sx,
                acc[r][0][2 * nd] + acc[r][0][2 * nd + 1],
                acc[r][1][2 * nd] + acc[r][1][2 * nd + 1],
                acc[r][2][2 * nd] + acc[r][2][2 * nd + 1],
                acc[r][3][2 * nd], acc[r][3][2 * nd + 1],
                crd[(size_t)(2 * n) * 128 + cc], crd[(size_t)(2 * n + 1) * 128 + cc]);
            if (lev == 5) {
              out_c[(size_t)blk * H_ + cc] = gt.cv;
              out_h8[(size_t)blk * H_ + cc] = f2bf(gt.hv);
            } else {
              cwr[(size_t)n * 128 + cc] = gt.cv;
              Awr[n][cc] = f2bf(gt.hv);
            }
          }
        }
      }
    }
    __syncthreads();
    R >>= 1;
  }
}

// ---- k_fin: levels 10-12 + fused projection; 64 blocks ----
__global__ void __launch_bounds__(512, 2) k_fin(
    const unsigned short* __restrict__ Wfrag, const float* __restrict__ symx,
    const int* __restrict__ symbols,
    const unsigned short* __restrict__ in_h8, const float* __restrict__ in_c,
    const float* __restrict__ Woutt, const float* __restrict__ bout,
    float* __restrict__ out) {
  __shared__ __align__(16) unsigned short Ah0[8][136];
  __shared__ __align__(16) unsigned short Ah1[4][136];
  __shared__ float Cs0[8][128];
  __shared__ float Cs1[4][128];
  __shared__ float rootv[128];
  int t = threadIdx.x;
  int w = t >> 6, L = t & 63, q = L >> 4, cL = L & 15;
  int cc = 16 * w + cL;
  int b = blockIdx.x;

  if (t < 128) {
    int row = t >> 4, co = (t & 15) * 8;
    *(int4*)&Ah0[row][co] = *(const int4*)(in_h8 + (size_t)(b * 8 + row) * H_ + co);
  }
  if (t < 256) {
    int row = t >> 5, c4 = (t & 31) << 2;
    *(float4*)&Cs0[row][c4] = *(const float4*)(in_c + (size_t)(b * 8 + row) * H_ + c4);
  }
  __syncthreads();

  const short8* wf = (const short8*)Wfrag;
  int R = 8;
  #pragma unroll
  for (int lev = 0; lev < 3; ++lev) {
    const int l = 10 + lev;
    const int nodes = R >> 1;
    const int jb = b * (N_ - 1) + (N_ - (N_ >> (l - 1)));
    unsigned short (*Ard)[136] = (lev & 1) ? Ah1 : Ah0;
    unsigned short (*Awr)[136] = (lev & 1) ? Ah0 : Ah1;
    const float* crd = (lev & 1) ? &Cs1[0][0] : &Cs0[0][0];
    float* cwr = (lev & 1) ? &Cs0[0][0] : &Cs1[0][0];
    int spre[4];
    #pragma unroll
    for (int it = 0; it < 4; ++it) {
      int n = 8 * (it >> 1) + 2 * q + (it & 1);
      spre[it] = (n < nodes) ? symbols[jb + n] : 0;
    }
    f32x4 acc[4];
    #pragma unroll
    for (int g = 0; g < 4; ++g) acc[g] = (f32x4){0.f, 0.f, 0.f, 0.f};
    #pragma unroll
    for (int K = 0; K < 4; ++K) {
      short8 bfr[4];
      #pragma unroll
      for (int g = 0; g < 4; ++g) bfr[g] = wf[(size_t)((w + 8 * g) * 4 + K) * 64 + L];
      short8 a0 = *(const short8*)&Ard[cL & 7][K * 32 + q * 8];
      #pragma unroll
      for (int g = 0; g < 4; ++g)
        acc[g] = __builtin_amdgcn_mfma_f32_16x16x32_bf16(a0, bfr[g], acc[g], 0, 0, 0);
    }
    #pragma unroll
    for (int nd = 0; nd < 2; ++nd) {
      int it = nd;
      int n = 2 * q + nd;
      if (n < nodes) {
        float4 sx = *(const float4*)(symx + (size_t)spre[it] * 512 + cc * 4);
        Gates gt = gate_combine(sx,
            acc[0][2 * nd] + acc[0][2 * nd + 1],
            acc[1][2 * nd] + acc[1][2 * nd + 1],
            acc[2][2 * nd] + acc[2][2 * nd + 1],
            acc[3][2 * nd], acc[3][2 * nd + 1],
            crd[(size_t)(2 * n) * 128 + cc], crd[(size_t)(2 * n + 1) * 128 + cc]);
        if (lev == 2) {
          rootv[cc] = gt.hv;
        } else {
          cwr[(size_t)n * 128 + cc] = gt.cv;
          Awr[n][cc] = f2bf(gt.hv);
        }
      }
    }
    __syncthreads();
    R >>= 1;
  }
  if (t < 128) {
    float acc = bout[t];
    for (int k = 0; k < H_; ++k) acc = fmaf(rootv[k], Woutt[k * 128 + t], acc);
    out[(size_t)b * H_ + t] = acc;
  }
}

extern "C" void kernel_launch(void* const* d_in, const int* in_sizes, int n_in,
                              void* d_out, int out_size, void* d_ws, size_t ws_size,
                              hipStream_t stream) {
  const int* tokens    = (const int*)d_in[0];
  const int* symbols   = (const int*)d_in[1];
  const float* emb     = (const float*)d_in[2];
  const float* sym_emb = (const float*)d_in[3];
  const float* Wp  = (const float*)d_in[4];
  const float* bp  = (const float*)d_in[5];
  const float* Wi  = (const float*)d_in[6];
  const float* bi  = (const float*)d_in[7];
  const float* Ui  = (const float*)d_in[8];
  const float* Wf  = (const float*)d_in[9];
  const float* bf  = (const float*)d_in[10];
  const float* Uf  = (const float*)d_in[11];
  const float* Wo  = (const float*)d_in[12];
  const float* bo  = (const float*)d_in[13];
  const float* Uo  = (const float*)d_in[14];
  const float* Wu  = (const float*)d_in[15];
  const float* bu  = (const float*)d_in[16];
  const float* Uu  = (const float*)d_in[17];
  const float* Wout= (const float*)d_in[18];
  const float* bout= (const float*)d_in[19];

  // Workspace layout (~45 MB)
  char* ws = (char*)d_ws;
  unsigned short* Wfrag   = (unsigned short*)(ws);                  // 131072
  float*          Wt      = (float*)(ws + 131072);                  // 262144
  float*          Wxt     = (float*)(ws + 393216);                  // 262144
  float*          Wpt     = (float*)(ws + 655360);                  // 32768
  float*          Woutt   = (float*)(ws + 688128);                  // 65536
  unsigned short* leaf_h8 = (unsigned short*)(ws + 753664);         // 5376
  float*          leaf_c  = (float*)(ws + 759040);                  // 10752
  float*          symx    = (float*)(ws + 769792);                  // 102400
  float*          P_leaf  = (float*)(ws + 872192);                  // 21*512*4 = 43008
  unsigned short* tab_h8  = (unsigned short*)(ws + 2001152UL);      // 5644800
  float*          tab_c   = (float*)(ws + 7645952UL);               // 11289600
  int*            idx1    = (int*)(ws + 18935552UL);                // 524288
  unsigned short* L3h8    = (unsigned short*)(ws + 19459840UL);     // 8388608
  float*          L3c     = (float*)(ws + 27848448UL);              // 16777216
  unsigned short* L9h8    = (unsigned short*)(ws + 44625664UL);     // 131072
  float*          L9c     = (float*)(ws + 44756736UL);              // 262144

  k_pre0<<<50, 512, 0, stream>>>(Ui, Uo, Uu, Uf, Wi, Wo, Wu, Wf, Wp, Wout,
                                 Wfrag, Wt, Wxt, Wpt, Woutt);
  k_pre1<<<V_ + S_, 512, 0, stream>>>(emb, sym_emb, Wpt, Wxt, Wt,
                                      bp, bi, bo, bu, bf,
                                      leaf_h8, leaf_c, symx, P_leaf);
  k_tabB<<<NTAB / 2 + 512, 256, 0, stream>>>(P_leaf, symx, leaf_c, tokens, symbols,
                                             tab_h8, tab_c, idx1);
  k_lvl23<<<2048, 512, 0, stream>>>(Wfrag, symx, symbols, idx1, tab_h8, tab_c, L3h8, L3c);
  k_mid<<<512, 512, 0, stream>>>(Wfrag, symx, symbols, L3h8, L3c, L9h8, L9c);
  k_fin<<<B_, 512, 0, stream>>>(Wfrag, symx, symbols, L9h8, L9c, Woutt, bout,
                                (float*)d_out);
}